// Round 5
// baseline (134.012 us; speedup 1.0000x reference)
//
#include <hip/hip_runtime.h>
#include <hip/hip_bf16.h>
#include <math.h>

typedef __attribute__((ext_vector_type(4))) float floatx4;

#define MARGIN_C    0.09f
#define ONE_M_EPS   0.99999f
#define NCLS        64
#define MEMSTRIDE   256

__device__ __forceinline__ unsigned short f2bf(float f) {
    unsigned u = __float_as_uint(f);
    u += 0x7fffu + ((u >> 16) & 1u);
    return (unsigned short)(u >> 16);
}
__device__ __forceinline__ float bf2f(unsigned short v) {
    return __uint_as_float(((unsigned)v) << 16);
}
// order-preserving float<->uint key for atomicMax on floats
__device__ __forceinline__ unsigned fkey(float f) {
    unsigned u = __float_as_uint(f);
    return (u >> 31) ? ~u : (u | 0x80000000u);
}
__device__ __forceinline__ float fdec(unsigned k) {
    return __uint_as_float((k >> 31) ? (k & 0x7fffffffu) : ~k);
}
__device__ __forceinline__ void gld16(const void* g, void* l) {
    __builtin_amdgcn_global_load_lds(
        (const __attribute__((address_space(1))) void*)g,
        (__attribute__((address_space(3))) void*)l, 16, 0, 0);
}

// ---------- fused: fp32->fp8 cvt + stat zeroing + out zeroing + member lists
__global__ __launch_bounds__(256) void cvt_build(const float* __restrict__ in,
                                                 unsigned* __restrict__ out8,   // 4 fp8 per uint
                                                 float* __restrict__ statz,     // negsum+negmax
                                                 const int* __restrict__ labels,
                                                 int* __restrict__ members,
                                                 int* __restrict__ classCount,
                                                 int* __restrict__ picls,
                                                 float* __restrict__ loss_out,
                                                 int n4, int nz4, int ncvt, int Bn) {
    __shared__ int cnt;
    const int bid = blockIdx.x;
    const int t = threadIdx.x;
    if (bid < ncvt) {
        int i = bid * 256 + t;
        if (bid == 0 && t == 0) loss_out[0] = 0.0f;
        if (i < nz4) ((float4*)statz)[i] = make_float4(0.f, 0.f, 0.f, 0.f);
        if (i >= n4) return;
        float4 v = ((const float4*)in)[i];
        int w = __builtin_amdgcn_cvt_pk_fp8_f32(v.x, v.y, 0, false);   // bytes 0,1
        w = __builtin_amdgcn_cvt_pk_fp8_f32(v.z, v.w, w, true);        // bytes 2,3
        out8[i] = (unsigned)w;
    } else {
        const int c = bid - ncvt;
        if (t == 0) cnt = 0;
        __syncthreads();
        for (int j = t; j < Bn; j += 256) {
            if (labels[j] == c) {
                int p = atomicAdd(&cnt, 1);
                if (p < MEMSTRIDE) members[c * MEMSTRIDE + p] = j;
                picls[j] = p;
            }
        }
        __syncthreads();
        if (t == 0) classCount[c] = (cnt < MEMSTRIDE) ? cnt : MEMSTRIDE;
    }
}

// ---------- GEMM, FP8 e4m3, 128x64 tiles, 512 threads (R19) -----------------
// R18 post-mortem: counted-vmcnt == drain-0 exactly (50.3 vs 50.4us, MfmaUtil
// 12.4 vs 12.0) -> schedule was NEVER the stall. OccupancyPercent pinned at
// 20% because the 528-block grid gives 2.06 blocks/CU: 2 waves/SIMD cannot
// hide the per-stage latency chain. Fix = wave count (m114, and R14's own
// history): back to the banded 1056-tile grid of 128x64, but 512-thread
// blocks of 8 waves, each wave a 32x32 sub-tile (acc[2][2], ~16 VGPR).
// 4 blocks/CU * 8 waves = 32 waves/CU = 8 waves/SIMD. LDS 25.5KB. Proven
// 2-barrier __syncthreads discipline, proven XOR swizzle, proven band map.
__global__ __launch_bounds__(512, 8) void gemm_fused(const unsigned char* __restrict__ fb8,
                                                     const int* __restrict__ labels,
                                                     const int* __restrict__ picls,
                                                     float* __restrict__ negsum,
                                                     unsigned* __restrict__ negmax,
                                                     unsigned short* __restrict__ posc,
                                                     int Bn, int Dn) {
    __shared__ __align__(16) unsigned char As[2][8192];   // [128 rows][64B] dbuf
    __shared__ __align__(16) unsigned char Bs[2][4096];   // [64 rows][64B] dbuf
    __shared__ int Lrow[128], Lcol[64];
    __shared__ int Prow[128], Pcol[64];

    // bid -> (by, c64): band by starts at by*(by+1), has 2*by+2 tiles
    const int bid = blockIdx.x;
    int by = (int)(sqrtf((float)bid + 0.25f) - 0.5f);
    while ((by + 1) * (by + 2) <= bid) by++;
    while (by * (by + 1) > bid) by--;
    const int c64 = bid - by * (by + 1);
    const int gcb = c64 * 64;                 // global col base
    const bool mirror = (gcb < by * 128);     // strictly left of diag block

    const int t = threadIdx.x;
    const int wave = t >> 6, lane = t & 63;
    const int quad = lane >> 4, m16 = lane & 15;
    const int wr = wave >> 1, wc = wave & 1;  // 4x2 waves over 128x64

    if (t < 128) {
        Lrow[t] = labels[by * 128 + t];
        Prow[t] = picls[by * 128 + t];
    } else if (t < 192) {
        Lcol[t - 128] = labels[gcb + (t - 128)];
        Pcol[t - 128] = picls[gcb + (t - 128)];
    }

    // staging: A = 128 rows x 4 granules (512 threads, 1 each); B = 64 rows x
    // 4 granules (threads 0..255). Global fetch XOR-swizzled so linear-LDS
    // ds_read_b64 fragments are conflict-free.
    const int rA = t >> 2, aA = t & 3;
    const int gofsA = ((2 * aA) ^ (rA & 6)) * 8;
    const unsigned char* gA0 = fb8 + (size_t)(by * 128 + rA) * Dn + gofsA;
    const unsigned char* gB0 = fb8 + (size_t)(gcb + (rA & 63)) * Dn + gofsA;
    const int lbA = t * 16;          // 0..8191
    const int lbB = (t & 255) * 16;  // 0..4095
    const bool doB = (t < 256);

    floatx4 acc[2][2];
#pragma unroll
    for (int i = 0; i < 2; i++)
#pragma unroll
        for (int j = 0; j < 2; j++) acc[i][j] = (floatx4){0.f, 0.f, 0.f, 0.f};

    // fragment reads: row stride 64B; logical half-chunk hc = quad + 4*kstep
    // lives at physical (hc ^ (m16&6))*8
    const int fragA = (wr * 32 + m16) * 64;
    const int fragB = (wc * 32 + m16) * 64;
    const int sw = m16 & 6;
    const int sK0 = (quad ^ sw) * 8;
    const int sK1 = ((quad + 4) ^ sw) * 8;

    const int NS = Dn / 64;   // 16 stages

    // prologue: DMA(0) -> buf 0
    gld16(gA0, &As[0][lbA]);
    if (doB) gld16(gB0, &Bs[0][lbB]);
    __syncthreads();   // drains DMA(0); labels visible

    for (int s = 0; s < NS; s++) {
        if (s + 1 < NS) {
            const int ko = (s + 1) * 64;
            const int nb = (s + 1) & 1;
            gld16(gA0 + ko, &As[nb][lbA]);
            if (doB) gld16(gB0 + ko, &Bs[nb][lbB]);
        }
        __builtin_amdgcn_sched_barrier(0);   // pin DMA issue before compute

        const unsigned char* as_ = &As[s & 1][0];
        const unsigned char* bs_ = &Bs[s & 1][0];
        long af[2], bfr[2];
        // k-step 0
#pragma unroll
        for (int i = 0; i < 2; i++) af[i]  = *(const long*)(as_ + fragA + i * 1024 + sK0);
#pragma unroll
        for (int j = 0; j < 2; j++) bfr[j] = *(const long*)(bs_ + fragB + j * 1024 + sK0);
#pragma unroll
        for (int i = 0; i < 2; i++)
#pragma unroll
            for (int j = 0; j < 2; j++)
                acc[i][j] = __builtin_amdgcn_mfma_f32_16x16x32_fp8_fp8(af[i], bfr[j], acc[i][j], 0, 0, 0);
        // k-step 1
#pragma unroll
        for (int i = 0; i < 2; i++) af[i]  = *(const long*)(as_ + fragA + i * 1024 + sK1);
#pragma unroll
        for (int j = 0; j < 2; j++) bfr[j] = *(const long*)(bs_ + fragB + j * 1024 + sK1);
#pragma unroll
        for (int i = 0; i < 2; i++)
#pragma unroll
            for (int j = 0; j < 2; j++)
                acc[i][j] = __builtin_amdgcn_mfma_f32_16x16x32_fp8_fp8(af[i], bfr[j], acc[i][j], 0, 0, 0);

        __syncthreads();   // drains DMA(s+1): issued one full stage ago
    }

    // ----- epilogue (C/D frag: col = wc*32 + j*16 + m16, row = wr*32 + i*16 + quad*4 + rr)
    int cl[2], gc[2], pc_[2];
#pragma unroll
    for (int j = 0; j < 2; j++) {
        const int c = wc * 32 + j * 16 + m16;
        cl[j] = Lcol[c];
        gc[j] = gcb + c;
        pc_[j] = Pcol[c];
    }

    float nsm[2] = {0.f, 0.f};
    float nmm[2] = {-INFINITY, -INFINITY};

#pragma unroll
    for (int i = 0; i < 2; i++) {
#pragma unroll
        for (int rr = 0; rr < 4; rr++) {
            const int rowl = wr * 32 + i * 16 + quad * 4 + rr;
            const int rl = Lrow[rowl];
            const int gr = by * 128 + rowl;
            float ns = 0.f, nm = -INFINITY;
#pragma unroll
            for (int j = 0; j < 2; j++) {
                const float s = acc[i][j][rr];
                if (cl[j] != rl) {
                    const float e = __expf(40.f * s);
                    ns += e;
                    nm = fmaxf(nm, s);
                    nsm[j] += e;
                    nmm[j] = fmaxf(nmm[j], s);
                } else if ((gr != gc[j]) & (s < ONE_M_EPS)) {
                    const unsigned short v = f2bf(s);
                    if (pc_[j] < MEMSTRIDE)
                        posc[(size_t)gr * MEMSTRIDE + pc_[j]] = v;
                    if (mirror) {
                        const int pr_ = Prow[rowl];
                        if (pr_ < MEMSTRIDE)
                            posc[(size_t)gc[j] * MEMSTRIDE + pr_] = v;
                    }
                }
            }
            // reduce the 16 m16-lanes of this quad-row (partial over 32 cols)
#pragma unroll
            for (int o = 8; o; o >>= 1) {
                ns += __shfl_down(ns, o, 64);
                nm = fmaxf(nm, __shfl_down(nm, o, 64));
            }
            if (m16 == 0) {   // two wc-waves per row merge via atomics
                atomicAdd(negsum + gr, ns);
                atomicMax(negmax + gr, fkey(nm));
            }
        }
    }
    if (mirror) {   // column stats feed rows gcb.. (strictly-left tiles only)
#pragma unroll
        for (int j = 0; j < 2; j++) {
            float v = nsm[j], m = nmm[j];
            v += __shfl_down(v, 16, 64);
            m = fmaxf(m, __shfl_down(m, 16, 64));
            v += __shfl_down(v, 32, 64);
            m = fmaxf(m, __shfl_down(m, 32, 64));
            if (quad == 0) {  // four wr-waves per col merge via atomics
                atomicAdd(negsum + gc[j], v);
                atomicMax(negmax + gc[j], fkey(m));
            }
        }
    }
}

// ---------- positives + per-row loss + mean: 1 row per wave -----------------
__global__ __launch_bounds__(256) void pos_final(const unsigned short* __restrict__ posc,
                                                 const int* __restrict__ labels,
                                                 const int* __restrict__ classCount,
                                                 const int* __restrict__ picls,
                                                 const unsigned* __restrict__ negmax,
                                                 const float* __restrict__ negsum,
                                                 float* __restrict__ out, int Bn) {
    __shared__ float part[4];
    const int t = threadIdx.x;
    const int wave = t >> 6, lane = t & 63;
    const int r = blockIdx.x * 4 + wave;

    const int lab = labels[r];
    const int selfp = picls[r];
    const float mx = fdec(negmax[r]);
    const float nsum = negsum[r];
    const int n = classCount[lab];
    const unsigned short* prow = posc + (size_t)r * MEMSTRIDE;

    float ps = 0.f, pc = 0.f;
    for (int j = lane; j < n; j += 64) {
        if (j != selfp) {
            const float s = bf2f(prow[j]);
            if ((s - MARGIN_C) < mx) {
                ps += __expf(-2.f * s);
                pc += 1.f;
            }
        }
    }
#pragma unroll
    for (int o = 32; o; o >>= 1) {
        ps += __shfl_down(ps, o, 64);
        pc += __shfl_down(pc, o, 64);
    }
    float wacc = 0.f;
    if (lane == 0) {
        const int nneg = Bn - n;
        if (nneg >= 1 && pc >= 0.5f) {
            float pl = 0.5f * logf((ps + expf(-2.f * 0.501f)) / (pc + 1.f));
            float nl = (1.f / 40.f) * logf((nsum + expf(40.f * 0.531f)) / ((float)nneg + 1.f));
            wacc = logf(5.33f + expf(pl + nl));
        }
        part[wave] = wacc;
    }
    __syncthreads();
    if (t == 0) {
        atomicAdd(out, (part[0] + part[1] + part[2] + part[3]) / (float)Bn);
    }
}

extern "C" void kernel_launch(void* const* d_in, const int* in_sizes, int n_in,
                              void* d_out, int out_size, void* d_ws, size_t ws_size,
                              hipStream_t stream) {
    const float* feats = (const float*)d_in[0];
    const int* labels  = (const int*)d_in[1];
    float* out = (float*)d_out;

    const int Bn = in_sizes[1];           // 4096
    const int Dn = in_sizes[0] / Bn;      // 1024

    unsigned char* fb8 = (unsigned char*)d_ws;                  // fp8 feats [Bn][Dn]
    float* stats    = (float*)(fb8 + (size_t)Bn * Dn);
    float* negsum   = stats;                                    // [Bn]
    unsigned* negmax = (unsigned*)(stats + Bn);                 // [Bn] keyed
    int* classCount = (int*)(stats + 2 * Bn);                   // [NCLS]
    int* members    = classCount + NCLS;                        // [NCLS][MEMSTRIDE]
    int* picls      = members + NCLS * MEMSTRIDE;               // [Bn] pos-in-class
    unsigned short* posc = (unsigned short*)(picls + Bn);       // [Bn][MEMSTRIDE] compact positives

    const int n4   = (Bn * Dn) / 4;
    const int nz4  = (2 * Bn) / 4;        // zero negsum+negmax
    const int ncvt = (n4 + 255) / 256;
    cvt_build<<<ncvt + NCLS, 256, 0, stream>>>(feats, (unsigned*)fb8, stats, labels,
                                               members, classCount, picls, out,
                                               n4, nz4, ncvt, Bn);

    const int nt = Bn / 128;              // 32 bands
    const int ngrid = nt * (nt + 1);      // 1056 tiles of 128x64
    gemm_fused<<<ngrid, 512, 0, stream>>>(fb8, labels, picls, negsum, negmax, posc, Bn, Dn);

    pos_final<<<Bn / 4, 256, 0, stream>>>(posc, labels, classCount, picls,
                                          negmax, negsum, out, Bn);
}

// Round 6
// 122.967 us; speedup vs baseline: 1.0898x; 1.0898x over previous
//
#include <hip/hip_runtime.h>
#include <hip/hip_bf16.h>
#include <math.h>

typedef __attribute__((ext_vector_type(4))) float floatx4;

#define MARGIN_C    0.09f
#define ONE_M_EPS   0.99999f
#define NCLS        64
#define MEMSTRIDE   256

__device__ __forceinline__ unsigned short f2bf(float f) {
    unsigned u = __float_as_uint(f);
    u += 0x7fffu + ((u >> 16) & 1u);
    return (unsigned short)(u >> 16);
}
__device__ __forceinline__ float bf2f(unsigned short v) {
    return __uint_as_float(((unsigned)v) << 16);
}
// order-preserving float<->uint key for atomicMax on floats
__device__ __forceinline__ unsigned fkey(float f) {
    unsigned u = __float_as_uint(f);
    return (u >> 31) ? ~u : (u | 0x80000000u);
}
__device__ __forceinline__ float fdec(unsigned k) {
    return __uint_as_float((k >> 31) ? (k & 0x7fffffffu) : ~k);
}
__device__ __forceinline__ void gld16(const void* g, void* l) {
    __builtin_amdgcn_global_load_lds(
        (const __attribute__((address_space(1))) void*)g,
        (__attribute__((address_space(3))) void*)l, 16, 0, 0);
}

// ---------- fused: fp32->fp8 cvt + stat zeroing + out zeroing + member lists
__global__ __launch_bounds__(256) void cvt_build(const float* __restrict__ in,
                                                 unsigned* __restrict__ out8,   // 4 fp8 per uint
                                                 float* __restrict__ statz,     // negsum+negmax
                                                 const int* __restrict__ labels,
                                                 int* __restrict__ members,
                                                 int* __restrict__ classCount,
                                                 int* __restrict__ picls,
                                                 float* __restrict__ loss_out,
                                                 int n4, int nz4, int ncvt, int Bn) {
    __shared__ int cnt;
    const int bid = blockIdx.x;
    const int t = threadIdx.x;
    if (bid < ncvt) {
        int i = bid * 256 + t;
        if (bid == 0 && t == 0) loss_out[0] = 0.0f;
        if (i < nz4) ((float4*)statz)[i] = make_float4(0.f, 0.f, 0.f, 0.f);
        if (i >= n4) return;
        float4 v = ((const float4*)in)[i];
        int w = __builtin_amdgcn_cvt_pk_fp8_f32(v.x, v.y, 0, false);   // bytes 0,1
        w = __builtin_amdgcn_cvt_pk_fp8_f32(v.z, v.w, w, true);        // bytes 2,3
        out8[i] = (unsigned)w;
    } else {
        const int c = bid - ncvt;
        if (t == 0) cnt = 0;
        __syncthreads();
        for (int j = t; j < Bn; j += 256) {
            if (labels[j] == c) {
                int p = atomicAdd(&cnt, 1);
                if (p < MEMSTRIDE) members[c * MEMSTRIDE + p] = j;
                picls[j] = p;
            }
        }
        __syncthreads();
        if (t == 0) classCount[c] = (cnt < MEMSTRIDE) ? cnt : MEMSTRIDE;
    }
}

// ---------- GEMM, FP8 e4m3, 128x64 tiles, 2 K-stages per barrier (R20) ------
// R17/R18/R19 post-mortems: gemm pinned at ~50us across tile shape, schedule,
// and 2->8 waves/SIMD. Slot arithmetic: 66 barrier-intervals/CU x ~1820cyc,
// content only ~300-500cyc -> the structure carries ~1400-1800cyc FIXED cost
// per interval (m97's 912TF kernel: same ~1400cyc/slot, but 64 K-stages to
// amortize; we have 16). Lever: fewer, fatter intervals. Quad-buffered LDS,
// prefetch stages s+2,s+3 at iter top, compute stages s,s+1, ONE syncthreads
// pair per 2 K-stages -> 8 intervals, 64 MFMAs/wave/interval. R0's proven
// 256-thread wave layout, 64B-row XOR swizzle, fragment code, __syncthreads
// discipline all unchanged; only the buffer index cycles mod 4. LDS 49.5KB ->
// 3 blocks/CU (R19 proved occupancy above this is irrelevant).
__global__ __launch_bounds__(256, 3) void gemm_fused(const unsigned char* __restrict__ fb8,
                                                     const int* __restrict__ labels,
                                                     const int* __restrict__ picls,
                                                     float* __restrict__ negsum,
                                                     unsigned* __restrict__ negmax,
                                                     unsigned short* __restrict__ posc,
                                                     int Bn, int Dn) {
    __shared__ __align__(16) unsigned char As[4][8192];   // [128 rows][64B] x4 k-chunks
    __shared__ __align__(16) unsigned char Bs[4][4096];   // [64 rows][64B]  x4 k-chunks
    __shared__ int Lrow[128], Lcol[64];
    __shared__ int Prow[128], Pcol[64];

    // bid -> (by, c64): band by starts at by*(by+1), has 2*by+2 tiles
    const int bid = blockIdx.x;
    int by = (int)(sqrtf((float)bid + 0.25f) - 0.5f);
    while ((by + 1) * (by + 2) <= bid) by++;
    while (by * (by + 1) > bid) by--;
    const int c64 = bid - by * (by + 1);
    const int gcb = c64 * 64;                 // global col base
    const bool mirror = (gcb < by * 128);     // strictly left of diag block

    const int t = threadIdx.x;
    const int wave = t >> 6, lane = t & 63;
    const int quad = lane >> 4, m16 = lane & 15;

    if (t < 128) {
        Lrow[t] = labels[by * 128 + t];
        Prow[t] = picls[by * 128 + t];
    } else if (t < 192) {
        Lcol[t - 128] = labels[gcb + (t - 128)];
        Pcol[t - 128] = picls[gcb + (t - 128)];
    }

    // staging: A rows r=t>>2 and r+64 (slot a=t&3); B rows r (64 rows, 1 granule).
    // Global fetch XOR-swizzled so linear-LDS ds_read_b64 frags are conflict-free.
    const int r = t >> 2, a = t & 3;
    const int gofs = ((2 * a) ^ (r & 6)) * 8;
    const unsigned char* gA0 = fb8 + (size_t)(by * 128 + r) * Dn + gofs;
    const unsigned char* gA1 = gA0 + (size_t)64 * Dn;
    const unsigned char* gB0 = fb8 + (size_t)(gcb + r) * Dn + gofs;
    const int lb = t * 16;   // bytes

    floatx4 acc[2][4];
#pragma unroll
    for (int i = 0; i < 2; i++)
#pragma unroll
        for (int j = 0; j < 4; j++) acc[i][j] = (floatx4){0.f, 0.f, 0.f, 0.f};

    // fragment reads: row stride 64B; logical half-chunk hc = quad + 4*kstep
    // lives at physical (hc ^ (m16&6))*8
    const int fragA = (wave * 32 + m16) * 64;
    const int fragB = m16 * 64;
    const int sw = m16 & 6;
    const int sK0 = (quad ^ sw) * 8;
    const int sK1 = ((quad + 4) ^ sw) * 8;

    const int NS = Dn / 64;   // 16 stages, processed 2 per barrier-interval

    // prologue: DMA stages 0,1 -> bufs 0,1 (6 gld16/thread)
    gld16(gA0, &As[0][lb]);
    gld16(gA1, &As[0][4096 + lb]);
    gld16(gB0, &Bs[0][lb]);
    gld16(gA0 + 64, &As[1][lb]);
    gld16(gA1 + 64, &As[1][4096 + lb]);
    gld16(gB0 + 64, &Bs[1][lb]);
    __syncthreads();   // drains prologue DMA; labels visible

    for (int s = 0; s < NS; s += 2) {
        if (s + 2 < NS) {
            const int ko2 = (s + 2) * 64;
            const int b2 = (s + 2) & 3;
            gld16(gA0 + ko2, &As[b2][lb]);
            gld16(gA1 + ko2, &As[b2][4096 + lb]);
            gld16(gB0 + ko2, &Bs[b2][lb]);
            const int ko3 = (s + 3) * 64;
            const int b3 = (s + 3) & 3;
            gld16(gA0 + ko3, &As[b3][lb]);
            gld16(gA1 + ko3, &As[b3][4096 + lb]);
            gld16(gB0 + ko3, &Bs[b3][lb]);
        }
        __builtin_amdgcn_sched_barrier(0);   // pin DMA issue before compute

        // ---- K-stage s (buf s&3)
        {
            const unsigned char* as_ = &As[s & 3][0];
            const unsigned char* bs_ = &Bs[s & 3][0];
            long af[2], bfr[4];
#pragma unroll
            for (int i = 0; i < 2; i++) af[i]  = *(const long*)(as_ + fragA + i * 1024 + sK0);
#pragma unroll
            for (int j = 0; j < 4; j++) bfr[j] = *(const long*)(bs_ + fragB + j * 1024 + sK0);
#pragma unroll
            for (int i = 0; i < 2; i++)
#pragma unroll
                for (int j = 0; j < 4; j++)
                    acc[i][j] = __builtin_amdgcn_mfma_f32_16x16x32_fp8_fp8(af[i], bfr[j], acc[i][j], 0, 0, 0);
#pragma unroll
            for (int i = 0; i < 2; i++) af[i]  = *(const long*)(as_ + fragA + i * 1024 + sK1);
#pragma unroll
            for (int j = 0; j < 4; j++) bfr[j] = *(const long*)(bs_ + fragB + j * 1024 + sK1);
#pragma unroll
            for (int i = 0; i < 2; i++)
#pragma unroll
                for (int j = 0; j < 4; j++)
                    acc[i][j] = __builtin_amdgcn_mfma_f32_16x16x32_fp8_fp8(af[i], bfr[j], acc[i][j], 0, 0, 0);
        }
        // ---- K-stage s+1 (buf (s+1)&3)
        {
            const unsigned char* as_ = &As[(s + 1) & 3][0];
            const unsigned char* bs_ = &Bs[(s + 1) & 3][0];
            long af[2], bfr[4];
#pragma unroll
            for (int i = 0; i < 2; i++) af[i]  = *(const long*)(as_ + fragA + i * 1024 + sK0);
#pragma unroll
            for (int j = 0; j < 4; j++) bfr[j] = *(const long*)(bs_ + fragB + j * 1024 + sK0);
#pragma unroll
            for (int i = 0; i < 2; i++)
#pragma unroll
                for (int j = 0; j < 4; j++)
                    acc[i][j] = __builtin_amdgcn_mfma_f32_16x16x32_fp8_fp8(af[i], bfr[j], acc[i][j], 0, 0, 0);
#pragma unroll
            for (int i = 0; i < 2; i++) af[i]  = *(const long*)(as_ + fragA + i * 1024 + sK1);
#pragma unroll
            for (int j = 0; j < 4; j++) bfr[j] = *(const long*)(bs_ + fragB + j * 1024 + sK1);
#pragma unroll
            for (int i = 0; i < 2; i++)
#pragma unroll
                for (int j = 0; j < 4; j++)
                    acc[i][j] = __builtin_amdgcn_mfma_f32_16x16x32_fp8_fp8(af[i], bfr[j], acc[i][j], 0, 0, 0);
        }

        __syncthreads();   // drains DMA(s+2,s+3); WAR guard for bufs (s,s+1)&3
    }

    // ----- single-pass epilogue (C/D: col = m16 + j*16, row = quad*4+rr + i*16)
    int cl[4], gc[4], pc_[4];
#pragma unroll
    for (int j = 0; j < 4; j++) {
        cl[j] = Lcol[j * 16 + m16];
        gc[j] = gcb + j * 16 + m16;
        pc_[j] = Pcol[j * 16 + m16];
    }

    float nsm[4] = {0.f, 0.f, 0.f, 0.f};
    float nmm[4] = {-INFINITY, -INFINITY, -INFINITY, -INFINITY};

#pragma unroll
    for (int i = 0; i < 2; i++) {
#pragma unroll
        for (int rr = 0; rr < 4; rr++) {
            const int rowl = wave * 32 + i * 16 + quad * 4 + rr;
            const int rl = Lrow[rowl];
            const int gr = by * 128 + rowl;
            float ns = 0.f, nm = -INFINITY;
#pragma unroll
            for (int j = 0; j < 4; j++) {
                const float s = acc[i][j][rr];
                if (cl[j] != rl) {
                    const float e = __expf(40.f * s);
                    ns += e;
                    nm = fmaxf(nm, s);
                    nsm[j] += e;
                    nmm[j] = fmaxf(nmm[j], s);
                } else if ((gr != gc[j]) & (s < ONE_M_EPS)) {
                    const unsigned short v = f2bf(s);
                    if (pc_[j] < MEMSTRIDE)
                        posc[(size_t)gr * MEMSTRIDE + pc_[j]] = v;
                    if (mirror) {
                        const int pr_ = Prow[rowl];
                        if (pr_ < MEMSTRIDE)
                            posc[(size_t)gc[j] * MEMSTRIDE + pr_] = v;
                    }
                }
            }
#pragma unroll
            for (int o = 8; o; o >>= 1) {
                ns += __shfl_down(ns, o, 64);
                nm = fmaxf(nm, __shfl_down(nm, o, 64));
            }
            if (m16 == 0) {
                atomicAdd(negsum + gr, ns);
                atomicMax(negmax + gr, fkey(nm));
            }
        }
    }
    if (mirror) {   // column stats feed rows gcb.. (only for strictly-left tiles)
#pragma unroll
        for (int j = 0; j < 4; j++) {
            float v = nsm[j], m = nmm[j];
            v += __shfl_down(v, 16, 64);
            m = fmaxf(m, __shfl_down(m, 16, 64));
            v += __shfl_down(v, 32, 64);
            m = fmaxf(m, __shfl_down(m, 32, 64));
            if (quad == 0) {
                atomicAdd(negsum + gc[j], v);
                atomicMax(negmax + gc[j], fkey(m));
            }
        }
    }
}

// ---------- positives + per-row loss + mean: 1 row per wave -----------------
__global__ __launch_bounds__(256) void pos_final(const unsigned short* __restrict__ posc,
                                                 const int* __restrict__ labels,
                                                 const int* __restrict__ classCount,
                                                 const int* __restrict__ picls,
                                                 const unsigned* __restrict__ negmax,
                                                 const float* __restrict__ negsum,
                                                 float* __restrict__ out, int Bn) {
    __shared__ float part[4];
    const int t = threadIdx.x;
    const int wave = t >> 6, lane = t & 63;
    const int r = blockIdx.x * 4 + wave;

    const int lab = labels[r];
    const int selfp = picls[r];
    const float mx = fdec(negmax[r]);
    const float nsum = negsum[r];
    const int n = classCount[lab];
    const unsigned short* prow = posc + (size_t)r * MEMSTRIDE;

    float ps = 0.f, pc = 0.f;
    for (int j = lane; j < n; j += 64) {
        if (j != selfp) {
            const float s = bf2f(prow[j]);
            if ((s - MARGIN_C) < mx) {
                ps += __expf(-2.f * s);
                pc += 1.f;
            }
        }
    }
#pragma unroll
    for (int o = 32; o; o >>= 1) {
        ps += __shfl_down(ps, o, 64);
        pc += __shfl_down(pc, o, 64);
    }
    float wacc = 0.f;
    if (lane == 0) {
        const int nneg = Bn - n;
        if (nneg >= 1 && pc >= 0.5f) {
            float pl = 0.5f * logf((ps + expf(-2.f * 0.501f)) / (pc + 1.f));
            float nl = (1.f / 40.f) * logf((nsum + expf(40.f * 0.531f)) / ((float)nneg + 1.f));
            wacc = logf(5.33f + expf(pl + nl));
        }
        part[wave] = wacc;
    }
    __syncthreads();
    if (t == 0) {
        atomicAdd(out, (part[0] + part[1] + part[2] + part[3]) / (float)Bn);
    }
}

extern "C" void kernel_launch(void* const* d_in, const int* in_sizes, int n_in,
                              void* d_out, int out_size, void* d_ws, size_t ws_size,
                              hipStream_t stream) {
    const float* feats = (const float*)d_in[0];
    const int* labels  = (const int*)d_in[1];
    float* out = (float*)d_out;

    const int Bn = in_sizes[1];           // 4096
    const int Dn = in_sizes[0] / Bn;      // 1024

    unsigned char* fb8 = (unsigned char*)d_ws;                  // fp8 feats [Bn][Dn]
    float* stats    = (float*)(fb8 + (size_t)Bn * Dn);
    float* negsum   = stats;                                    // [Bn]
    unsigned* negmax = (unsigned*)(stats + Bn);                 // [Bn] keyed
    int* classCount = (int*)(stats + 2 * Bn);                   // [NCLS]
    int* members    = classCount + NCLS;                        // [NCLS][MEMSTRIDE]
    int* picls      = members + NCLS * MEMSTRIDE;               // [Bn] pos-in-class
    unsigned short* posc = (unsigned short*)(picls + Bn);       // [Bn][MEMSTRIDE] compact positives

    const int n4   = (Bn * Dn) / 4;
    const int nz4  = (2 * Bn) / 4;        // zero negsum+negmax
    const int ncvt = (n4 + 255) / 256;
    cvt_build<<<ncvt + NCLS, 256, 0, stream>>>(feats, (unsigned*)fb8, stats, labels,
                                               members, classCount, picls, out,
                                               n4, nz4, ncvt, Bn);

    const int nt = Bn / 128;              // 32 bands
    const int ngrid = nt * (nt + 1);      // 1056 tiles of 128x64
    gemm_fused<<<ngrid, 256, 0, stream>>>(fb8, labels, picls, negsum, negmax, posc, Bn, Dn);

    pos_final<<<Bn / 4, 256, 0, stream>>>(posc, labels, classCount, picls,
                                          negmax, negsum, out, Bn);
}

// Round 7
// 114.236 us; speedup vs baseline: 1.1731x; 1.0764x over previous
//
#include <hip/hip_runtime.h>
#include <hip/hip_bf16.h>
#include <math.h>

typedef __attribute__((ext_vector_type(4))) float floatx4;

#define MARGIN_C    0.09f
#define ONE_M_EPS   0.99999f
#define NCLS        64
#define MEMSTRIDE   256

__device__ __forceinline__ unsigned short f2bf(float f) {
    unsigned u = __float_as_uint(f);
    u += 0x7fffu + ((u >> 16) & 1u);
    return (unsigned short)(u >> 16);
}
__device__ __forceinline__ float bf2f(unsigned short v) {
    return __uint_as_float(((unsigned)v) << 16);
}
// order-preserving float<->uint key for atomicMax on floats
__device__ __forceinline__ unsigned fkey(float f) {
    unsigned u = __float_as_uint(f);
    return (u >> 31) ? ~u : (u | 0x80000000u);
}
__device__ __forceinline__ float fdec(unsigned k) {
    return __uint_as_float((k >> 31) ? (k & 0x7fffffffu) : ~k);
}
__device__ __forceinline__ void gld16(const void* g, void* l) {
    __builtin_amdgcn_global_load_lds(
        (const __attribute__((address_space(1))) void*)g,
        (__attribute__((address_space(3))) void*)l, 16, 0, 0);
}

// ---------- fused: fp32->fp8 cvt + stat zeroing + out zeroing + member lists
__global__ __launch_bounds__(256) void cvt_build(const float* __restrict__ in,
                                                 unsigned* __restrict__ out8,   // 4 fp8 per uint
                                                 float* __restrict__ statz,     // negsum+negmax
                                                 const int* __restrict__ labels,
                                                 int* __restrict__ members,
                                                 int* __restrict__ classCount,
                                                 float* __restrict__ loss_out,
                                                 int n4, int nz4, int ncvt, int Bn) {
    __shared__ int cnt;
    const int bid = blockIdx.x;
    const int t = threadIdx.x;
    if (bid < ncvt) {
        int i = bid * 256 + t;
        if (bid == 0 && t == 0) loss_out[0] = 0.0f;
        if (i < nz4) ((float4*)statz)[i] = make_float4(0.f, 0.f, 0.f, 0.f);
        if (i >= n4) return;
        float4 v = ((const float4*)in)[i];
        int w = __builtin_amdgcn_cvt_pk_fp8_f32(v.x, v.y, 0, false);   // bytes 0,1
        w = __builtin_amdgcn_cvt_pk_fp8_f32(v.z, v.w, w, true);        // bytes 2,3
        out8[i] = (unsigned)w;
    } else {
        const int c = bid - ncvt;
        if (t == 0) cnt = 0;
        __syncthreads();
        for (int j = t; j < Bn; j += 256) {
            if (labels[j] == c) {
                int p = atomicAdd(&cnt, 1);
                if (p < MEMSTRIDE) members[c * MEMSTRIDE + p] = j;
            }
        }
        __syncthreads();
        if (t == 0) classCount[c] = (cnt < MEMSTRIDE) ? cnt : MEMSTRIDE;
    }
}

// ---------- GEMM, FP8 e4m3, 128x64 tiles (R21 = R0 champion + quad-buffer) --
// R21: byte-identical to the 107.9us champion EXCEPT the K-loop is
// quad-buffered with 2 K-stages per barrier-interval: 8 intervals instead of
// 16. Rationale: R17/R18/R19 showed gemm time is invariant to schedule and
// occupancy but scales with barrier-interval count (R20: 50 -> <43.5us when
// intervals halved on the posc variant). Each interval: prefetch stages
// s+2,s+3 (6 gld16/thread), compute stages s,s+1 (32 MFMAs/wave), one
// __syncthreads. Buffers {s,s+1} (read) and {s+2,s+3} (DMA) are disjoint
// mod 4; the end-of-interval barrier (vmcnt0 drain) covers WAR + visibility.
// LDS 48KB+labels -> 3 blocks/CU (R19: occupancy >2-3 blocks is not the
// limiter). Everything else (swizzle, fragments, epilogue, pairsim,
// pos_final) is the champion's, untouched, for clean A/B attribution.
__global__ __launch_bounds__(256, 3) void gemm_fused(const unsigned char* __restrict__ fb8,
                                                     const int* __restrict__ labels,
                                                     float* __restrict__ negsum,
                                                     unsigned* __restrict__ negmax,
                                                     unsigned short* __restrict__ pairsim,
                                                     int Bn, int Dn) {
    __shared__ __align__(16) unsigned char As[4][8192];   // [128 rows][64B] x4 k-chunks
    __shared__ __align__(16) unsigned char Bs[4][4096];   // [64 rows][64B]  x4 k-chunks
    __shared__ int Lrow[128], Lcol[64];

    // bid -> (by, c64): band by starts at by*(by+1), has 2*by+2 tiles
    const int bid = blockIdx.x;
    int by = (int)(sqrtf((float)bid + 0.25f) - 0.5f);
    while ((by + 1) * (by + 2) <= bid) by++;
    while (by * (by + 1) > bid) by--;
    const int c64 = bid - by * (by + 1);
    const int gcb = c64 * 64;                 // global col base
    const bool mirror = (gcb < by * 128);     // strictly left of diag block

    const int t = threadIdx.x;
    const int wave = t >> 6, lane = t & 63;
    const int quad = lane >> 4, m16 = lane & 15;

    if (t < 128) Lrow[t] = labels[by * 128 + t];
    else if (t < 192) Lcol[t - 128] = labels[gcb + (t - 128)];

    // staging: A rows r=t>>2 and r+64 (slot a=t&3); B rows r (64 rows, 1 granule).
    // Global fetch XOR-swizzled so linear-LDS ds_read_b64 frags are conflict-free.
    const int r = t >> 2, a = t & 3;
    const int gofs = ((2 * a) ^ (r & 6)) * 8;
    const unsigned char* gA0 = fb8 + (size_t)(by * 128 + r) * Dn + gofs;
    const unsigned char* gA1 = gA0 + (size_t)64 * Dn;
    const unsigned char* gB0 = fb8 + (size_t)(gcb + r) * Dn + gofs;
    const int lb = t * 16;   // bytes

    floatx4 acc[2][4];
#pragma unroll
    for (int i = 0; i < 2; i++)
#pragma unroll
        for (int j = 0; j < 4; j++) acc[i][j] = (floatx4){0.f, 0.f, 0.f, 0.f};

    // fragment reads: row stride 64B; logical half-chunk hc = quad + 4*kstep
    // lives at physical (hc ^ (m16&6))*8
    const int fragA = (wave * 32 + m16) * 64;
    const int fragB = m16 * 64;
    const int sw = m16 & 6;
    const int sK0 = (quad ^ sw) * 8;
    const int sK1 = ((quad + 4) ^ sw) * 8;

    const int NS = Dn / 64;   // 16 stages, processed 2 per barrier-interval

    // prologue: DMA stages 0,1 -> bufs 0,1 (6 gld16/thread)
    gld16(gA0, &As[0][lb]);
    gld16(gA1, &As[0][4096 + lb]);
    gld16(gB0, &Bs[0][lb]);
    gld16(gA0 + 64, &As[1][lb]);
    gld16(gA1 + 64, &As[1][4096 + lb]);
    gld16(gB0 + 64, &Bs[1][lb]);
    __syncthreads();   // drains prologue DMA; labels visible

    for (int s = 0; s < NS; s += 2) {
        if (s + 2 < NS) {
            const int ko2 = (s + 2) * 64;
            const int b2 = (s + 2) & 3;
            gld16(gA0 + ko2, &As[b2][lb]);
            gld16(gA1 + ko2, &As[b2][4096 + lb]);
            gld16(gB0 + ko2, &Bs[b2][lb]);
            const int ko3 = (s + 3) * 64;
            const int b3 = (s + 3) & 3;
            gld16(gA0 + ko3, &As[b3][lb]);
            gld16(gA1 + ko3, &As[b3][4096 + lb]);
            gld16(gB0 + ko3, &Bs[b3][lb]);
        }
        __builtin_amdgcn_sched_barrier(0);   // pin DMA issue before compute

        // ---- K-stage s (buf s&3)
        {
            const unsigned char* as_ = &As[s & 3][0];
            const unsigned char* bs_ = &Bs[s & 3][0];
            long af[2], bfr[4];
#pragma unroll
            for (int i = 0; i < 2; i++) af[i]  = *(const long*)(as_ + fragA + i * 1024 + sK0);
#pragma unroll
            for (int j = 0; j < 4; j++) bfr[j] = *(const long*)(bs_ + fragB + j * 1024 + sK0);
#pragma unroll
            for (int i = 0; i < 2; i++)
#pragma unroll
                for (int j = 0; j < 4; j++)
                    acc[i][j] = __builtin_amdgcn_mfma_f32_16x16x32_fp8_fp8(af[i], bfr[j], acc[i][j], 0, 0, 0);
#pragma unroll
            for (int i = 0; i < 2; i++) af[i]  = *(const long*)(as_ + fragA + i * 1024 + sK1);
#pragma unroll
            for (int j = 0; j < 4; j++) bfr[j] = *(const long*)(bs_ + fragB + j * 1024 + sK1);
#pragma unroll
            for (int i = 0; i < 2; i++)
#pragma unroll
                for (int j = 0; j < 4; j++)
                    acc[i][j] = __builtin_amdgcn_mfma_f32_16x16x32_fp8_fp8(af[i], bfr[j], acc[i][j], 0, 0, 0);
        }
        // ---- K-stage s+1 (buf (s+1)&3)
        {
            const unsigned char* as_ = &As[(s + 1) & 3][0];
            const unsigned char* bs_ = &Bs[(s + 1) & 3][0];
            long af[2], bfr[4];
#pragma unroll
            for (int i = 0; i < 2; i++) af[i]  = *(const long*)(as_ + fragA + i * 1024 + sK0);
#pragma unroll
            for (int j = 0; j < 4; j++) bfr[j] = *(const long*)(bs_ + fragB + j * 1024 + sK0);
#pragma unroll
            for (int i = 0; i < 2; i++)
#pragma unroll
                for (int j = 0; j < 4; j++)
                    acc[i][j] = __builtin_amdgcn_mfma_f32_16x16x32_fp8_fp8(af[i], bfr[j], acc[i][j], 0, 0, 0);
#pragma unroll
            for (int i = 0; i < 2; i++) af[i]  = *(const long*)(as_ + fragA + i * 1024 + sK1);
#pragma unroll
            for (int j = 0; j < 4; j++) bfr[j] = *(const long*)(bs_ + fragB + j * 1024 + sK1);
#pragma unroll
            for (int i = 0; i < 2; i++)
#pragma unroll
                for (int j = 0; j < 4; j++)
                    acc[i][j] = __builtin_amdgcn_mfma_f32_16x16x32_fp8_fp8(af[i], bfr[j], acc[i][j], 0, 0, 0);
        }

        __syncthreads();   // drains DMA(s+2,s+3); WAR guard for bufs (s,s+1)&3
    }

    // ----- single-pass epilogue (C/D: col = m16 + j*16, row = quad*4+rr + i*16)
    int cl[4], gc[4];
#pragma unroll
    for (int j = 0; j < 4; j++) {
        cl[j] = Lcol[j * 16 + m16];
        gc[j] = gcb + j * 16 + m16;
    }

    float nsm[4] = {0.f, 0.f, 0.f, 0.f};
    float nmm[4] = {-INFINITY, -INFINITY, -INFINITY, -INFINITY};

#pragma unroll
    for (int i = 0; i < 2; i++) {
#pragma unroll
        for (int rr = 0; rr < 4; rr++) {
            const int rowl = wave * 32 + i * 16 + quad * 4 + rr;
            const int rl = Lrow[rowl];
            const int gr = by * 128 + rowl;
            float ns = 0.f, nm = -INFINITY;
#pragma unroll
            for (int j = 0; j < 4; j++) {
                const float s = acc[i][j][rr];
                if (cl[j] != rl) {
                    const float e = __expf(40.f * s);
                    ns += e;
                    nm = fmaxf(nm, s);
                    nsm[j] += e;
                    nmm[j] = fmaxf(nmm[j], s);
                } else if ((gr != gc[j]) & (s < ONE_M_EPS)) {
                    const unsigned short v = f2bf(s);
                    pairsim[(size_t)gr * Bn + gc[j]] = v;
                    if (mirror) pairsim[(size_t)gc[j] * Bn + gr] = v;
                }
            }
#pragma unroll
            for (int o = 8; o; o >>= 1) {
                ns += __shfl_down(ns, o, 64);
                nm = fmaxf(nm, __shfl_down(nm, o, 64));
            }
            if (m16 == 0) {
                atomicAdd(negsum + gr, ns);
                atomicMax(negmax + gr, fkey(nm));
            }
        }
    }
    if (mirror) {   // column stats feed rows gcb.. (only for strictly-left tiles)
#pragma unroll
        for (int j = 0; j < 4; j++) {
            float v = nsm[j], m = nmm[j];
            v += __shfl_down(v, 16, 64);
            m = fmaxf(m, __shfl_down(m, 16, 64));
            v += __shfl_down(v, 32, 64);
            m = fmaxf(m, __shfl_down(m, 32, 64));
            if (quad == 0) {
                atomicAdd(negsum + gc[j], v);
                atomicMax(negmax + gc[j], fkey(m));
            }
        }
    }
}

// ---------- positives + per-row loss + mean, merged (16 rows/block) ---------
__global__ __launch_bounds__(256) void pos_final(const unsigned short* __restrict__ pairsim,
                                                 const int* __restrict__ labels,
                                                 const int* __restrict__ members,
                                                 const int* __restrict__ classCount,
                                                 const unsigned* __restrict__ negmax,
                                                 const float* __restrict__ negsum,
                                                 float* __restrict__ out, int Bn) {
    __shared__ float part[4];
    const int t = threadIdx.x;
    const int wave = t >> 6, lane = t & 63;
    float wacc = 0.f;
#pragma unroll
    for (int rr = 0; rr < 4; rr++) {
        const int r = blockIdx.x * 16 + wave * 4 + rr;
        if (r >= Bn) break;
        const int lab = labels[r];
        const int n = classCount[lab];
        const int base = lab * MEMSTRIDE;
        const float mx = fdec(negmax[r]);
        const unsigned short* prow = pairsim + (size_t)r * Bn;

        float ps = 0.f, pc = 0.f;
        for (int j = lane; j < n; j += 64) {
            const int m = members[base + j];
            if (m != r) {
                const float s = bf2f(prow[m]);
                if ((s - MARGIN_C) < mx) {
                    ps += __expf(-2.f * s);
                    pc += 1.f;
                }
            }
        }
#pragma unroll
        for (int o = 32; o; o >>= 1) {
            ps += __shfl_down(ps, o, 64);
            pc += __shfl_down(pc, o, 64);
        }
        if (lane == 0) {
            const int nneg = Bn - n;
            if (nneg >= 1 && pc >= 0.5f) {
                float pl = 0.5f * logf((ps + expf(-2.f * 0.501f)) / (pc + 1.f));
                float nl = (1.f / 40.f) * logf((negsum[r] + expf(40.f * 0.531f)) / ((float)nneg + 1.f));
                wacc += logf(5.33f + expf(pl + nl));
            }
        }
    }
    if (lane == 0) part[wave] = wacc;
    __syncthreads();
    if (t == 0) {
        atomicAdd(out, (part[0] + part[1] + part[2] + part[3]) / (float)Bn);
    }
}

extern "C" void kernel_launch(void* const* d_in, const int* in_sizes, int n_in,
                              void* d_out, int out_size, void* d_ws, size_t ws_size,
                              hipStream_t stream) {
    const float* feats = (const float*)d_in[0];
    const int* labels  = (const int*)d_in[1];
    float* out = (float*)d_out;

    const int Bn = in_sizes[1];           // 4096
    const int Dn = in_sizes[0] / Bn;      // 1024

    unsigned char* fb8 = (unsigned char*)d_ws;                  // fp8 feats [Bn][Dn]
    float* stats    = (float*)(fb8 + (size_t)Bn * Dn);
    float* negsum   = stats;                                    // [Bn]
    unsigned* negmax = (unsigned*)(stats + Bn);                 // [Bn] keyed
    int* classCount = (int*)(stats + 2 * Bn);                   // [NCLS]
    int* members    = classCount + NCLS;                        // [NCLS][MEMSTRIDE]
    unsigned short* pairsim = (unsigned short*)(members + NCLS * MEMSTRIDE); // [Bn][Bn]

    const int n4   = (Bn * Dn) / 4;
    const int nz4  = (2 * Bn) / 4;        // zero negsum+negmax
    const int ncvt = (n4 + 255) / 256;
    cvt_build<<<ncvt + NCLS, 256, 0, stream>>>(feats, (unsigned*)fb8, stats, labels,
                                               members, classCount, out,
                                               n4, nz4, ncvt, Bn);

    const int nt = Bn / 128;              // 32 bands
    const int ngrid = nt * (nt + 1);      // 1056 tiles of 128x64
    gemm_fused<<<ngrid, 256, 0, stream>>>(fb8, labels, negsum, negmax, pairsim, Bn, Dn);

    pos_final<<<(Bn + 15) / 16, 256, 0, stream>>>(pairsim, labels, members, classCount,
                                                  negmax, negsum, out, Bn);
}

// Round 8
// 109.128 us; speedup vs baseline: 1.2280x; 1.0468x over previous
//
#include <hip/hip_runtime.h>
#include <hip/hip_bf16.h>
#include <math.h>

typedef __attribute__((ext_vector_type(4))) float floatx4;

#define MARGIN_C    0.09f
#define ONE_M_EPS   0.99999f
#define NCLS        64
#define MEMSTRIDE   256

__device__ __forceinline__ unsigned short f2bf(float f) {
    unsigned u = __float_as_uint(f);
    u += 0x7fffu + ((u >> 16) & 1u);
    return (unsigned short)(u >> 16);
}
__device__ __forceinline__ float bf2f(unsigned short v) {
    return __uint_as_float(((unsigned)v) << 16);
}
// order-preserving float<->uint key for atomicMax on floats
__device__ __forceinline__ unsigned fkey(float f) {
    unsigned u = __float_as_uint(f);
    return (u >> 31) ? ~u : (u | 0x80000000u);
}
__device__ __forceinline__ float fdec(unsigned k) {
    return __uint_as_float((k >> 31) ? (k & 0x7fffffffu) : ~k);
}
__device__ __forceinline__ void gld16(const void* g, void* l) {
    __builtin_amdgcn_global_load_lds(
        (const __attribute__((address_space(1))) void*)g,
        (__attribute__((address_space(3))) void*)l, 16, 0, 0);
}

// ---------- fused: fp32->fp8 cvt + stat zeroing + out zeroing + member lists
__global__ __launch_bounds__(256) void cvt_build(const float* __restrict__ in,
                                                 unsigned* __restrict__ out8,   // 4 fp8 per uint
                                                 float* __restrict__ statz,     // negsum+negmax
                                                 const int* __restrict__ labels,
                                                 int* __restrict__ members,
                                                 int* __restrict__ classCount,
                                                 float* __restrict__ loss_out,
                                                 int n4, int nz4, int ncvt, int Bn) {
    __shared__ int cnt;
    const int bid = blockIdx.x;
    const int t = threadIdx.x;
    if (bid < ncvt) {
        int i = bid * 256 + t;
        if (bid == 0 && t == 0) loss_out[0] = 0.0f;
        if (i < nz4) ((float4*)statz)[i] = make_float4(0.f, 0.f, 0.f, 0.f);
        if (i >= n4) return;
        float4 v = ((const float4*)in)[i];
        int w = __builtin_amdgcn_cvt_pk_fp8_f32(v.x, v.y, 0, false);   // bytes 0,1
        w = __builtin_amdgcn_cvt_pk_fp8_f32(v.z, v.w, w, true);        // bytes 2,3
        out8[i] = (unsigned)w;
    } else {
        const int c = bid - ncvt;
        if (t == 0) cnt = 0;
        __syncthreads();
        for (int j = t; j < Bn; j += 256) {
            if (labels[j] == c) {
                int p = atomicAdd(&cnt, 1);
                if (p < MEMSTRIDE) members[c * MEMSTRIDE + p] = j;
            }
        }
        __syncthreads();
        if (t == 0) classCount[c] = (cnt < MEMSTRIDE) ? cnt : MEMSTRIDE;
    }
}

// ---------- GEMM, FP8 e4m3, 128x64 tiles (R22 = R0 champion + XCD swizzle) --
// Eight-round ledger: every structural variant (128x128 tile, counted vmcnt,
// 512-thread/44% occupancy, quad-buffer) measured 49-52us @ MfmaUtil ~12.5%;
// only this dbuf 4-blocks/CU structure stays under the 43us fill cutoff.
// Schedule/occupancy/interval-count are all falsified levers -> revert
// byte-for-byte to the 107.9us champion and change ONE thing:
// XCD-aware bijective blockIdx swizzle (T1). HW round-robins consecutive
// blockIdx across 8 XCDs, so every XCD's L2 re-fetches every A-band panel
// (R7 FETCH 21MB = 5x the 4MB fb8). bid=(hw&7)*132+hw/8 gives each XCD 132
// CONSECUTIVE tiles = 2-3 whole bands -> A-panels L2-resident per XCD.
// Atomics/pairsim writes are order-independent: swizzle is correctness-neutral.
__global__ __launch_bounds__(256, 4) void gemm_fused(const unsigned char* __restrict__ fb8,
                                                     const int* __restrict__ labels,
                                                     float* __restrict__ negsum,
                                                     unsigned* __restrict__ negmax,
                                                     unsigned short* __restrict__ pairsim,
                                                     int Bn, int Dn) {
    __shared__ __align__(16) unsigned char As[2][8192];   // [128 rows][64B] dbuf
    __shared__ __align__(16) unsigned char Bs[2][4096];   // [64 rows][64B] dbuf
    __shared__ int Lrow[128], Lcol[64];

    // XCD swizzle: nwg = 1056 = 8*132 exactly -> bijective chunked remap.
    const int cpx = (int)(gridDim.x >> 3);          // 132 tiles per XCD
    const int hw  = blockIdx.x;
    const int bid = (hw & 7) * cpx + (hw >> 3);

    // bid -> (by, c64): band by starts at by*(by+1), has 2*by+2 tiles
    int by = (int)(sqrtf((float)bid + 0.25f) - 0.5f);
    while ((by + 1) * (by + 2) <= bid) by++;
    while (by * (by + 1) > bid) by--;
    const int c64 = bid - by * (by + 1);
    const int gcb = c64 * 64;                 // global col base
    const bool mirror = (gcb < by * 128);     // strictly left of diag block

    const int t = threadIdx.x;
    const int wave = t >> 6, lane = t & 63;
    const int quad = lane >> 4, m16 = lane & 15;

    if (t < 128) Lrow[t] = labels[by * 128 + t];
    else if (t < 192) Lcol[t - 128] = labels[gcb + (t - 128)];

    // staging: A rows r=t>>2 and r+64 (slot a=t&3); B rows r (64 rows, 1 granule).
    // Global fetch XOR-swizzled so linear-LDS ds_read_b64 frags are conflict-free.
    const int r = t >> 2, a = t & 3;
    const int gofs = ((2 * a) ^ (r & 6)) * 8;
    const unsigned char* gA0 = fb8 + (size_t)(by * 128 + r) * Dn + gofs;
    const unsigned char* gA1 = gA0 + (size_t)64 * Dn;
    const unsigned char* gB0 = fb8 + (size_t)(gcb + r) * Dn + gofs;
    const int lb = t * 16;   // bytes

    floatx4 acc[2][4];
#pragma unroll
    for (int i = 0; i < 2; i++)
#pragma unroll
        for (int j = 0; j < 4; j++) acc[i][j] = (floatx4){0.f, 0.f, 0.f, 0.f};

    // fragment reads: row stride 64B; logical half-chunk hc = quad + 4*kstep
    // lives at physical (hc ^ (m16&6))*8
    const int fragA = (wave * 32 + m16) * 64;
    const int fragB = m16 * 64;
    const int sw = m16 & 6;
    const int sK0 = (quad ^ sw) * 8;
    const int sK1 = ((quad + 4) ^ sw) * 8;

    const int NS = Dn / 64;   // 16 stages

    // prologue: DMA(0) -> buf 0 (3 gld16/thread)
    gld16(gA0, &As[0][lb]);
    gld16(gA1, &As[0][4096 + lb]);
    gld16(gB0, &Bs[0][lb]);
    __syncthreads();   // drains DMA(0); labels visible

    for (int s = 0; s < NS; s++) {
        if (s + 1 < NS) {
            const int ko = (s + 1) * 64;
            const int nb = (s + 1) & 1;
            gld16(gA0 + ko, &As[nb][lb]);
            gld16(gA1 + ko, &As[nb][4096 + lb]);
            gld16(gB0 + ko, &Bs[nb][lb]);
        }
        __builtin_amdgcn_sched_barrier(0);   // pin DMA issue before compute

        const unsigned char* as_ = &As[s & 1][0];
        const unsigned char* bs_ = &Bs[s & 1][0];
        long af[2], bfr[4];
        // k-step 0
#pragma unroll
        for (int i = 0; i < 2; i++) af[i]  = *(const long*)(as_ + fragA + i * 1024 + sK0);
#pragma unroll
        for (int j = 0; j < 4; j++) bfr[j] = *(const long*)(bs_ + fragB + j * 1024 + sK0);
#pragma unroll
        for (int i = 0; i < 2; i++)
#pragma unroll
            for (int j = 0; j < 4; j++)
                acc[i][j] = __builtin_amdgcn_mfma_f32_16x16x32_fp8_fp8(af[i], bfr[j], acc[i][j], 0, 0, 0);
        // k-step 1
#pragma unroll
        for (int i = 0; i < 2; i++) af[i]  = *(const long*)(as_ + fragA + i * 1024 + sK1);
#pragma unroll
        for (int j = 0; j < 4; j++) bfr[j] = *(const long*)(bs_ + fragB + j * 1024 + sK1);
#pragma unroll
        for (int i = 0; i < 2; i++)
#pragma unroll
            for (int j = 0; j < 4; j++)
                acc[i][j] = __builtin_amdgcn_mfma_f32_16x16x32_fp8_fp8(af[i], bfr[j], acc[i][j], 0, 0, 0);

        __syncthreads();   // drains DMA(s+1): issued one full stage ago
    }

    // ----- single-pass epilogue (C/D: col = m16 + j*16, row = quad*4+rr + i*16)
    int cl[4], gc[4];
#pragma unroll
    for (int j = 0; j < 4; j++) {
        cl[j] = Lcol[j * 16 + m16];
        gc[j] = gcb + j * 16 + m16;
    }

    float nsm[4] = {0.f, 0.f, 0.f, 0.f};
    float nmm[4] = {-INFINITY, -INFINITY, -INFINITY, -INFINITY};

#pragma unroll
    for (int i = 0; i < 2; i++) {
#pragma unroll
        for (int rr = 0; rr < 4; rr++) {
            const int rowl = wave * 32 + i * 16 + quad * 4 + rr;
            const int rl = Lrow[rowl];
            const int gr = by * 128 + rowl;
            float ns = 0.f, nm = -INFINITY;
#pragma unroll
            for (int j = 0; j < 4; j++) {
                const float s = acc[i][j][rr];
                if (cl[j] != rl) {
                    const float e = __expf(40.f * s);
                    ns += e;
                    nm = fmaxf(nm, s);
                    nsm[j] += e;
                    nmm[j] = fmaxf(nmm[j], s);
                } else if ((gr != gc[j]) & (s < ONE_M_EPS)) {
                    const unsigned short v = f2bf(s);
                    pairsim[(size_t)gr * Bn + gc[j]] = v;
                    if (mirror) pairsim[(size_t)gc[j] * Bn + gr] = v;
                }
            }
#pragma unroll
            for (int o = 8; o; o >>= 1) {
                ns += __shfl_down(ns, o, 64);
                nm = fmaxf(nm, __shfl_down(nm, o, 64));
            }
            if (m16 == 0) {
                atomicAdd(negsum + gr, ns);
                atomicMax(negmax + gr, fkey(nm));
            }
        }
    }
    if (mirror) {   // column stats feed rows gcb.. (only for strictly-left tiles)
#pragma unroll
        for (int j = 0; j < 4; j++) {
            float v = nsm[j], m = nmm[j];
            v += __shfl_down(v, 16, 64);
            m = fmaxf(m, __shfl_down(m, 16, 64));
            v += __shfl_down(v, 32, 64);
            m = fmaxf(m, __shfl_down(m, 32, 64));
            if (quad == 0) {
                atomicAdd(negsum + gc[j], v);
                atomicMax(negmax + gc[j], fkey(m));
            }
        }
    }
}

// ---------- positives + per-row loss + mean, merged (16 rows/block) ---------
__global__ __launch_bounds__(256) void pos_final(const unsigned short* __restrict__ pairsim,
                                                 const int* __restrict__ labels,
                                                 const int* __restrict__ members,
                                                 const int* __restrict__ classCount,
                                                 const unsigned* __restrict__ negmax,
                                                 const float* __restrict__ negsum,
                                                 float* __restrict__ out, int Bn) {
    __shared__ float part[4];
    const int t = threadIdx.x;
    const int wave = t >> 6, lane = t & 63;
    float wacc = 0.f;
#pragma unroll
    for (int rr = 0; rr < 4; rr++) {
        const int r = blockIdx.x * 16 + wave * 4 + rr;
        if (r >= Bn) break;
        const int lab = labels[r];
        const int n = classCount[lab];
        const int base = lab * MEMSTRIDE;
        const float mx = fdec(negmax[r]);
        const unsigned short* prow = pairsim + (size_t)r * Bn;

        float ps = 0.f, pc = 0.f;
        for (int j = lane; j < n; j += 64) {
            const int m = members[base + j];
            if (m != r) {
                const float s = bf2f(prow[m]);
                if ((s - MARGIN_C) < mx) {
                    ps += __expf(-2.f * s);
                    pc += 1.f;
                }
            }
        }
#pragma unroll
        for (int o = 32; o; o >>= 1) {
            ps += __shfl_down(ps, o, 64);
            pc += __shfl_down(pc, o, 64);
        }
        if (lane == 0) {
            const int nneg = Bn - n;
            if (nneg >= 1 && pc >= 0.5f) {
                float pl = 0.5f * logf((ps + expf(-2.f * 0.501f)) / (pc + 1.f));
                float nl = (1.f / 40.f) * logf((negsum[r] + expf(40.f * 0.531f)) / ((float)nneg + 1.f));
                wacc += logf(5.33f + expf(pl + nl));
            }
        }
    }
    if (lane == 0) part[wave] = wacc;
    __syncthreads();
    if (t == 0) {
        atomicAdd(out, (part[0] + part[1] + part[2] + part[3]) / (float)Bn);
    }
}

extern "C" void kernel_launch(void* const* d_in, const int* in_sizes, int n_in,
                              void* d_out, int out_size, void* d_ws, size_t ws_size,
                              hipStream_t stream) {
    const float* feats = (const float*)d_in[0];
    const int* labels  = (const int*)d_in[1];
    float* out = (float*)d_out;

    const int Bn = in_sizes[1];           // 4096
    const int Dn = in_sizes[0] / Bn;      // 1024

    unsigned char* fb8 = (unsigned char*)d_ws;                  // fp8 feats [Bn][Dn]
    float* stats    = (float*)(fb8 + (size_t)Bn * Dn);
    float* negsum   = stats;                                    // [Bn]
    unsigned* negmax = (unsigned*)(stats + Bn);                 // [Bn] keyed
    int* classCount = (int*)(stats + 2 * Bn);                   // [NCLS]
    int* members    = classCount + NCLS;                        // [NCLS][MEMSTRIDE]
    unsigned short* pairsim = (unsigned short*)(members + NCLS * MEMSTRIDE); // [Bn][Bn]

    const int n4   = (Bn * Dn) / 4;
    const int nz4  = (2 * Bn) / 4;        // zero negsum+negmax
    const int ncvt = (n4 + 255) / 256;
    cvt_build<<<ncvt + NCLS, 256, 0, stream>>>(feats, (unsigned*)fb8, stats, labels,
                                               members, classCount, out,
                                               n4, nz4, ncvt, Bn);

    const int nt = Bn / 128;              // 32 bands
    const int ngrid = nt * (nt + 1);      // 1056 tiles of 128x64 (multiple of 8)
    gemm_fused<<<ngrid, 256, 0, stream>>>(fb8, labels, negsum, negmax, pairsim, Bn, Dn);

    pos_final<<<(Bn + 15) / 16, 256, 0, stream>>>(pairsim, labels, members, classCount,
                                                  negmax, negsum, out, Bn);
}